// Round 4
// baseline (65.177 us; speedup 1.0000x reference)
//
#include <hip/hip_runtime.h>
#include <math.h>

// np.float32(sqrt(2)) == 0x3FB504F3
#define SQRT2F   1.41421356237309504880f
#define EPSF     1e-32f
#define BTOL     3e-5f   // f32 fast-path x_log error is <~3e-6 in the decision-
                         // relevant range |x_log|<=~12; band is 10x that

// C=4096 rows, F=4096 cols, 4 contiguous elements per thread (within one row).
__global__ __launch_bounds__(256) void uaq_kernel(
    const float4* __restrict__ x,
    const float*  __restrict__ scale,     // (C,)
    const float4* __restrict__ zero,
    const float4* __restrict__ code,
    const float4* __restrict__ level,
    const float*  __restrict__ asym,      // (C,)
    float4* __restrict__ out,
    int n4)
{
    int i = blockIdx.x * blockDim.x + threadIdx.x;
    if (i >= n4) return;

    int row = i >> 10;                    // F/4 = 1024
    float sc = scale[row];
    float lo = -1.0f - 0.5f * asym[row];  // exact: asym in {0,1}

    float4 xv = x[i];
    float4 zv = zero[i];
    float4 cv = code[i];
    float4 lv = level[i];
    float4 ov;

    const float* xp = &xv.x;
    const float* zp = &zv.x;
    const float* cp = &cv.x;
    const float* lp = &lv.x;
    float* op = &ov.x;

    #pragma unroll
    for (int k = 0; k < 4; ++k) {
        float xe = xp[k], ze = zp[k], ce = cp[k], le = lp[k];

        // mirror numpy f32 exactly for the non-transcendental part:
        // ax = |x/scale| (IEEE f32 div), axe = ax + eps (IEEE f32 add)
        float ax  = fabsf(xe / sc);
        float axe = ax + EPSF;

        // fast f32 estimate of x_log (device logf, ~1 ulp)
        float xlg = logf(axe) / logf(ce);
        float fr  = xlg - floorf(xlg);
        float xi;
        if (fabsf(fr - 0.5f) < BTOL) {
            // Emulate idealized float32 numpy near the round-half boundary:
            //   L32 = correctly-rounded f32 log(axe)   (f64 log, round to f32)
            //   D32 = correctly-rounded f32 log(code)
            //   q32 = IEEE f32 division
            //   rintf = round-half-EVEN — reproduces np.round's banker's
            //   rounding at the exact f32 tie values (n+0.5) where the f32
            //   reference actually lands on them.
            float L32 = (float)log((double)axe);
            float D32 = (float)log((double)ce);
            float q32 = L32 / D32;
            xi = rintf(q32);
        } else {
            xi = rintf(xlg);              // all impls agree away from boundary
        }

        float xc1 = fmaxf(xi - ze, lo);          // clamp(min=lo)
        float xc  = fminf(xc1 - le, -1.0f);      // clamp(max=-1)
        float e   = xc + le + ze;                // integer in [-1,9] unless zeroed

        bool  is_s2 = (ce == SQRT2F);
        float q;
        if (is_s2) {
            // approx_factor * sqrt(2) == 1.5 exactly:
            //   e even: q = 2^(e/2);  e odd: q = 1.5 * 2^((e-1)/2)
            int ei = (int)e;
            q = (ei & 1) ? ldexpf(1.5f, (ei - 1) >> 1)
                         : ldexpf(1.0f, ei >> 1);
        } else {
            q = powf(ce, e);                     // generic fallback (unused here)
        }

        float s = (xe > 0.0f) ? 1.0f : ((xe < 0.0f) ? -1.0f : 0.0f);
        if (xc1 <= lo) q = 0.0f;                 // zero_flag (covers non-integer e)

        op[k] = q * s * sc;
    }

    out[i] = ov;
}

extern "C" void kernel_launch(void* const* d_in, const int* in_sizes, int n_in,
                              void* d_out, int out_size, void* d_ws, size_t ws_size,
                              hipStream_t stream) {
    const float* x     = (const float*)d_in[0];
    const float* scale = (const float*)d_in[1];
    const float* zero  = (const float*)d_in[2];
    const float* code  = (const float*)d_in[3];
    const float* level = (const float*)d_in[4];
    const float* asym  = (const float*)d_in[5];
    float* out = (float*)d_out;

    int n  = out_size;          // 4096*4096
    int n4 = n / 4;

    int block = 256;
    int grid  = (n4 + block - 1) / block;

    uaq_kernel<<<grid, block, 0, stream>>>(
        (const float4*)x, scale, (const float4*)zero, (const float4*)code,
        (const float4*)level, asym, (float4*)out, n4);
}